// Round 4
// baseline (367.431 us; speedup 1.0000x reference)
//
#include <hip/hip_runtime.h>

#define BATCH 64
#define HH 512
#define WW 512
#define TH 32                  // output rows per strip
#define KS 11
#define PADK 5
#define NIN (TH + 2 * PADK)    // 42 input rows per strip
#define NF4 262                // float4 slots/row: 3 pad + 256 px-pairs + 3 pad
#define NPIX (64.0 * 512.0 * 512.0)

// 256 threads; thread t owns output cols 2t,2t+1 of a TH=32-row strip.
// LDS: 4-row chunks, double-buffered (2*4*4192 = 33.5 KB) -> 4 blocks/CU,
// matching the 4 work-blocks/CU exactly (kills the 3-resident/4-work tail
// that held round 3 at 20% occupancy). Staging is DIRECT global->LDS
// (float4{a0,b0,a1,b1} per px pair; 16 waves/CU of TLP hide the latency).
// Vertical ring: 12-deep (96 NAMED scalars; arrays would hit scratch via
// SROA-before-unroll). lcm(4-row chunk, 12 ring) = 12 rows = 3 chunks ->
// inner group of 12 static row bodies, outer loop x4, buffers swapped via
// LDS pointer (no code duplication for parity).
__global__ void __launch_bounds__(256, 4) ssim_main_kernel(
    const float* __restrict__ img1, const float* __restrict__ img2,
    double* __restrict__ accum) {
  constexpr float GA[KS] = {
      0.00102838f, 0.00759884f, 0.03600087f, 0.10936069f, 0.21300553f,
      0.26601172f, 0.21300553f, 0.10936069f, 0.03600087f, 0.00759884f,
      0.00102838f};
  const float C1v = 1e-4f, C2v = 9e-4f;

  const int t  = threadIdx.x;          // 0..255
  const int r0 = blockIdx.x * TH;      // first output row of strip
  const int b  = blockIdx.y;           // batch index

  const float2* __restrict__ pp1 =
      reinterpret_cast<const float2*>(img1 + (size_t)b * HH * WW);
  const float2* __restrict__ pp2 =
      reinterpret_cast<const float2*>(img2 + (size_t)b * HH * WW);

  __shared__ float4 sh[2][4][NF4];   // px pair (2x,2x+1) -> slot x+3
  __shared__ float wsum[4];

  // Zero horizontal pads of both buffers (slots 0..2, 259..261; never
  // overwritten afterwards).
  if (t < 6) {
    const int idx = (t < 3) ? t : (256 + t);
#pragma unroll
    for (int bi = 0; bi < 2; ++bi)
#pragma unroll
      for (int r = 0; r < 4; ++r) sh[bi][r][idx] = make_float4(0.f, 0.f, 0.f, 0.f);
  }

  // Ring: 96 named scalars; slot s holds h-conv of input row i, i%12==s.
#define DECLR(s) float xA##s = 0.f, xB##s = 0.f, xQ##s = 0.f, xP##s = 0.f, \
                       yA##s = 0.f, yB##s = 0.f, yQ##s = 0.f, yP##s = 0.f;
  DECLR(0) DECLR(1) DECLR(2) DECLR(3) DECLR(4) DECLR(5)
  DECLR(6) DECLR(7) DECLR(8) DECLR(9) DECLR(10) DECLR(11)

  float local = 0.f;

  // Stage row r_ of chunk k1_ directly into dst_ (1 b128 ds_write; rows
  // beyond NIN skipped entirely — they are never read). Guards are
  // block-uniform scalar branches.
#define STG1(k1_, r_, dst_)                                              \
  {                                                                      \
    const int rc_ = 4 * (k1_) + (r_);                                    \
    if (rc_ < NIN) {                                                     \
      const int rr_ = r0 - PADK + rc_;                                   \
      float2 va_ = make_float2(0.f, 0.f);                                \
      float2 vb_ = make_float2(0.f, 0.f);                                \
      if ((unsigned)rr_ < HH) {                                          \
        const int off_ = rr_ * (WW / 2) + t;                             \
        va_ = pp1[off_];                                                 \
        vb_ = pp2[off_];                                                 \
      }                                                                  \
      dst_[r_][t + 3] = make_float4(va_.x, vb_.x, va_.y, vb_.y);         \
    }                                                                    \
  }
#define STAGE(k1_, dst_) { STG1(k1_, 0, dst_) STG1(k1_, 1, dst_) \
                           STG1(k1_, 2, dst_) STG1(k1_, 3, dst_) }

  // Horizontal conv of LDS row p_ of cur -> ring slot S. 7 b128 reads;
  // f4 slot t+kk = px pair (j0=2kk-1, j1=2kk) rel. to window start 2t-5;
  // col0 (2t) taps GA[j], col1 (2t+1) taps GA[j-1]. (Verified round 3.)
#define HBODY(p_, S)                                                          \
  {                                                                           \
    float h0a = 0.f, h0b = 0.f, h0q = 0.f, h0p = 0.f;                         \
    float h1a = 0.f, h1b = 0.f, h1q = 0.f, h1p = 0.f;                         \
    _Pragma("unroll")                                                         \
    for (int kk = 0; kk < 7; ++kk) {                                          \
      const float4 v = cur[p_][t + kk];                                       \
      if (kk >= 1) { /* px j0 = 2kk-1 : a=v.x b=v.y */                        \
        const float qv_ = fmaf(v.x, v.x, v.y * v.y);                          \
        const float pv_ = v.x * v.y;                                          \
        if (kk <= 5) {                                                        \
          const float w = GA[2 * kk - 1];                                     \
          h0a = fmaf(w, v.x, h0a); h0b = fmaf(w, v.y, h0b);                   \
          h0q = fmaf(w, qv_, h0q); h0p = fmaf(w, pv_, h0p);                   \
        }                                                                     \
        {                                                                     \
          const float w = GA[2 * kk - 2];                                     \
          h1a = fmaf(w, v.x, h1a); h1b = fmaf(w, v.y, h1b);                   \
          h1q = fmaf(w, qv_, h1q); h1p = fmaf(w, pv_, h1p);                   \
        }                                                                     \
      }                                                                       \
      if (kk <= 5) { /* px j1 = 2kk : a=v.z b=v.w */                          \
        const float qv_ = fmaf(v.z, v.z, v.w * v.w);                          \
        const float pv_ = v.z * v.w;                                          \
        {                                                                     \
          const float w = GA[2 * kk];                                         \
          h0a = fmaf(w, v.z, h0a); h0b = fmaf(w, v.w, h0b);                   \
          h0q = fmaf(w, qv_, h0q); h0p = fmaf(w, pv_, h0p);                   \
        }                                                                     \
        if (kk >= 1) {                                                        \
          const float w = GA[2 * kk - 1];                                     \
          h1a = fmaf(w, v.z, h1a); h1b = fmaf(w, v.w, h1b);                   \
          h1q = fmaf(w, qv_, h1q); h1p = fmaf(w, pv_, h1p);                   \
        }                                                                     \
      }                                                                       \
    }                                                                         \
    xA##S = h0a; xB##S = h0b; xQ##S = h0q; xP##S = h0p;                       \
    yA##S = h1a; yB##S = h1b; yQ##S = h1q; yP##S = h1p;                       \
  }

  // Vertical conv: explicit rotation, all slot names literal.
#define VC(P, s0,s1,s2v,s3,s4v,s5,s6v,s7,s8,s9,s10)                           \
  fmaf(GA[10], P##s10, fmaf(GA[9], P##s9, fmaf(GA[8], P##s8,                  \
  fmaf(GA[7], P##s7, fmaf(GA[6], P##s6v, fmaf(GA[5], P##s5,                   \
  fmaf(GA[4], P##s4v, fmaf(GA[3], P##s3, fmaf(GA[2], P##s2v,                  \
  fmaf(GA[1], P##s1, GA[0] * P##s0))))))))))

#define SSIMACC                                                               \
  {                                                                           \
    const float m1s = m1 * m1, m2s = m2 * m2, m12 = m1 * m2;                  \
    const float s12 = mp - m12;                                               \
    const float sqq = mq - m1s - m2s;                                         \
    const float num = fmaf(2.f, m12, C1v) * fmaf(2.f, s12, C2v);              \
    const float den = (m1s + m2s + C1v) * (sqq + C2v);                        \
    local = fmaf(num, __builtin_amdgcn_rcpf(den), local);                     \
  }

#define VOUTBODY(s0,s1,s2v,s3,s4v,s5,s6v,s7,s8,s9,s10)                        \
  {                                                                           \
    {                                                                         \
      const float m1 = VC(xA, s0,s1,s2v,s3,s4v,s5,s6v,s7,s8,s9,s10);          \
      const float m2 = VC(xB, s0,s1,s2v,s3,s4v,s5,s6v,s7,s8,s9,s10);          \
      const float mq = VC(xQ, s0,s1,s2v,s3,s4v,s5,s6v,s7,s8,s9,s10);          \
      const float mp = VC(xP, s0,s1,s2v,s3,s4v,s5,s6v,s7,s8,s9,s10);          \
      SSIMACC                                                                 \
    }                                                                         \
    {                                                                         \
      const float m1 = VC(yA, s0,s1,s2v,s3,s4v,s5,s6v,s7,s8,s9,s10);          \
      const float m2 = VC(yB, s0,s1,s2v,s3,s4v,s5,s6v,s7,s8,s9,s10);          \
      const float mq = VC(yQ, s0,s1,s2v,s3,s4v,s5,s6v,s7,s8,s9,s10);          \
      const float mp = VC(yP, s0,s1,s2v,s3,s4v,s5,s6v,s7,s8,s9,s10);          \
      SSIMACC                                                                 \
    }                                                                         \
  }

  // Row body: h-conv into ring slot S from LDS row p_ of cur, then (if
  // cond_ — block-uniform) vertical conv + SSIM for output row i-10.
  // Rotation: output row i taps ring slots (i+2+tap)%12, i%12 == S.
#define ROWB(p_, S, cond_, s0,s1,s2v,s3,s4v,s5,s6v,s7,s8,s9,s10)              \
  {                                                                           \
    HBODY(p_, S)                                                              \
    if (cond_) VOUTBODY(s0,s1,s2v,s3,s4v,s5,s6v,s7,s8,s9,s10)                 \
  }

  // Prologue: stage chunk 0 into buffer 0.
  float4 (*cur)[NF4] = sh[0];
  float4 (*nxt)[NF4] = sh[1];
  STAGE(0, cur)
  __syncthreads();

  // 12 chunks of 4 rows (48 slots; rows >= NIN guarded off). One barrier
  // per chunk; each group g handles rows 12g..12g+11 = ring slots 0..11.
#pragma unroll 1
  for (int g = 0; g < 4; ++g) {
    // chunk c=0: rows 12g+0..3 = slots 0..3
    STAGE(3 * g + 1, nxt)
    ROWB(0, 0, (g > 0), 2,3,4,5,6,7,8,9,10,11,0)
    ROWB(1, 1, (g > 0), 3,4,5,6,7,8,9,10,11,0,1)
    ROWB(2, 2, (g > 0), 4,5,6,7,8,9,10,11,0,1,2)
    ROWB(3, 3, (g > 0), 5,6,7,8,9,10,11,0,1,2,3)
    __syncthreads();
    { float4 (*tmp)[NF4] = cur; cur = nxt; nxt = tmp; }

    // chunk c=1: rows 12g+4..7 = slots 4..7 (rows 42+ phantom at g=3)
    STAGE(3 * g + 2, nxt)
    ROWB(0, 4, (g > 0), 6,7,8,9,10,11,0,1,2,3,4)
    ROWB(1, 5, (g > 0), 7,8,9,10,11,0,1,2,3,4,5)
    if (g < 3) {
      ROWB(2, 6, (g > 0), 8,9,10,11,0,1,2,3,4,5,6)
      ROWB(3, 7, (g > 0), 9,10,11,0,1,2,3,4,5,6,7)
    }
    __syncthreads();
    { float4 (*tmp)[NF4] = cur; cur = nxt; nxt = tmp; }

    // chunk c=2: rows 12g+8..11 = slots 8..11 (all phantom at g=3)
    STAGE(3 * g + 3, nxt)
    if (g < 3) {
      ROWB(0, 8,  (g > 0), 10,11,0,1,2,3,4,5,6,7,8)
      ROWB(1, 9,  (g > 0), 11,0,1,2,3,4,5,6,7,8,9)
      ROWB(2, 10, true,    0,1,2,3,4,5,6,7,8,9,10)
      ROWB(3, 11, true,    1,2,3,4,5,6,7,8,9,10,11)
    }
    __syncthreads();
    { float4 (*tmp)[NF4] = cur; cur = nxt; nxt = tmp; }
  }

  // Block reduction: wave64 shuffle -> LDS -> one double atomic per block.
#pragma unroll
  for (int off = 32; off > 0; off >>= 1) local += __shfl_down(local, off, 64);
  const int wave = t >> 6;
  const int lane = t & 63;
  if (lane == 0) wsum[wave] = local;
  __syncthreads();
  if (t == 0) {
    float s = wsum[0] + wsum[1] + wsum[2] + wsum[3];
    atomicAdd(accum, (double)s);
  }
}

__global__ void ssim_final_kernel(const double* __restrict__ accum,
                                  float* __restrict__ out) {
  out[0] = 1.0f - (float)(accum[0] / NPIX);
}

extern "C" void kernel_launch(void* const* d_in, const int* in_sizes, int n_in,
                              void* d_out, int out_size, void* d_ws, size_t ws_size,
                              hipStream_t stream) {
  const float* img1 = (const float*)d_in[0];
  const float* img2 = (const float*)d_in[1];
  double* accum = (double*)d_ws;
  hipMemsetAsync(accum, 0, sizeof(double), stream);

  dim3 grid(HH / TH, BATCH);
  ssim_main_kernel<<<grid, 256, 0, stream>>>(img1, img2, accum);
  ssim_final_kernel<<<1, 1, 0, stream>>>(accum, (float*)d_out);
}

// Round 5
// 212.193 us; speedup vs baseline: 1.7316x; 1.7316x over previous
//
#include <hip/hip_runtime.h>

#define BATCH 64
#define HH 512
#define WW 512
#define TH 32                  // output rows per strip
#define KS 11
#define PADK 5
#define NIN (TH + 2 * PADK)    // 42 input rows per strip
#define NF4 262                // float4 slots/row: 3 pad + 256 px-pairs + 3 pad
#define NPIX (64.0 * 512.0 * 512.0)

// 256 threads; thread t owns output cols 2t,2t+1 of a TH=32-row strip.
// LDS: 4-row chunks double-buffered (2*4*4192 = 33.5 KB) -> 4 blocks/CU =
// exactly the 4 work-blocks/CU (kills round-3's 3-resident tail).
// Registers: ring-11 = 88 NAMED scalars + reg-staged prefetch — the exact
// configuration round 3 measured at 92 VGPR, zero scratch. NO tight
// launch_bounds cap (round 4's (256,4) cap triggered wholesale spill:
// 386 MB scratch writes). lcm(4,11)=44 -> 11 chunks fully unrolled with
// literal buffer parity (k&1) and literal ring rotations.
__global__ void __launch_bounds__(256, 2) ssim_main_kernel(
    const float* __restrict__ img1, const float* __restrict__ img2,
    double* __restrict__ accum) {
  constexpr float GA[KS] = {
      0.00102838f, 0.00759884f, 0.03600087f, 0.10936069f, 0.21300553f,
      0.26601172f, 0.21300553f, 0.10936069f, 0.03600087f, 0.00759884f,
      0.00102838f};
  const float C1v = 1e-4f, C2v = 9e-4f;

  const int t  = threadIdx.x;          // 0..255
  const int r0 = blockIdx.x * TH;      // first output row of strip
  const int b  = blockIdx.y;           // batch index

  const float2* __restrict__ pp1 =
      reinterpret_cast<const float2*>(img1 + (size_t)b * HH * WW);
  const float2* __restrict__ pp2 =
      reinterpret_cast<const float2*>(img2 + (size_t)b * HH * WW);

  __shared__ float4 sh[2][4][NF4];   // px pair (2x,2x+1) -> slot x+3
  __shared__ float wsum[4];

  // Zero horizontal pads of both buffers once (slots 0..2 and 259..261).
  if (t < 6) {
    const int idx = (t < 3) ? t : (256 + t);
#pragma unroll
    for (int bi = 0; bi < 2; ++bi)
#pragma unroll
      for (int r = 0; r < 4; ++r) sh[bi][r][idx] = make_float4(0.f, 0.f, 0.f, 0.f);
  }

  // Ring: 88 named scalars; slot s holds h-conv of input row rc, rc%11==s.
#define DECLR(s) float xA##s = 0.f, xB##s = 0.f, xQ##s = 0.f, xP##s = 0.f, \
                       yA##s = 0.f, yB##s = 0.f, yQ##s = 0.f, yP##s = 0.f;
  DECLR(0) DECLR(1) DECLR(2) DECLR(3) DECLR(4) DECLR(5)
  DECLR(6) DECLR(7) DECLR(8) DECLR(9) DECLR(10)

  float2 ta0, ta1, ta2, ta3, tb0, tb1, tb2, tb3;  // T14 staging regs
  float local = 0.f;

  // Load chunk k_ rows into regs (rows >= NIN constexpr-skipped; row
  // validity is block-uniform).
#define LD1(k_, j_)                                                     \
  {                                                                     \
    constexpr int rc_ = 4 * (k_) + (j_);                                \
    ta##j_ = make_float2(0.f, 0.f);                                     \
    tb##j_ = make_float2(0.f, 0.f);                                     \
    if constexpr (rc_ < NIN) {                                          \
      const int rr_ = r0 - PADK + rc_;                                  \
      if ((unsigned)rr_ < HH) {                                         \
        const int off_ = rr_ * (WW / 2) + t;                            \
        ta##j_ = pp1[off_];                                             \
        tb##j_ = pp2[off_];                                             \
      }                                                                 \
    }                                                                   \
  }
#define LOADC(k_) { LD1(k_, 0) LD1(k_, 1) LD1(k_, 2) LD1(k_, 3) }

  // Write staged regs of chunk k_ into buffer k_&1 (1 b128 ds_write/row).
#define WR1(k_, j_)                                                     \
  {                                                                     \
    constexpr int rc_ = 4 * (k_) + (j_);                                \
    if constexpr (rc_ < NIN)                                            \
      sh[(k_) & 1][j_][t + 3] =                                         \
          make_float4(ta##j_.x, tb##j_.x, ta##j_.y, tb##j_.y);          \
  }
#define WRITEC(k_) { WR1(k_, 0) WR1(k_, 1) WR1(k_, 2) WR1(k_, 3) }

  // Horizontal conv of LDS row j_ of buffer B_ -> ring slot S. 7 b128
  // reads; f4 slot t+kk = px pair (j0=2kk-1, j1=2kk) rel. to window start
  // 2t-5; col0 (2t) taps GA[j], col1 (2t+1) GA[j-1]. (Verified round 3.)
#define HBODY(B_, j_, S)                                                      \
  {                                                                           \
    float h0a = 0.f, h0b = 0.f, h0q = 0.f, h0p = 0.f;                         \
    float h1a = 0.f, h1b = 0.f, h1q = 0.f, h1p = 0.f;                         \
    _Pragma("unroll")                                                         \
    for (int kk = 0; kk < 7; ++kk) {                                          \
      const float4 v = sh[B_][j_][t + kk];                                    \
      if (kk >= 1) { /* px j0 = 2kk-1 : a=v.x b=v.y */                        \
        const float qv_ = fmaf(v.x, v.x, v.y * v.y);                          \
        const float pv_ = v.x * v.y;                                          \
        if (kk <= 5) {                                                        \
          const float w = GA[2 * kk - 1];                                     \
          h0a = fmaf(w, v.x, h0a); h0b = fmaf(w, v.y, h0b);                   \
          h0q = fmaf(w, qv_, h0q); h0p = fmaf(w, pv_, h0p);                   \
        }                                                                     \
        {                                                                     \
          const float w = GA[2 * kk - 2];                                     \
          h1a = fmaf(w, v.x, h1a); h1b = fmaf(w, v.y, h1b);                   \
          h1q = fmaf(w, qv_, h1q); h1p = fmaf(w, pv_, h1p);                   \
        }                                                                     \
      }                                                                       \
      if (kk <= 5) { /* px j1 = 2kk : a=v.z b=v.w */                          \
        const float qv_ = fmaf(v.z, v.z, v.w * v.w);                          \
        const float pv_ = v.z * v.w;                                          \
        {                                                                     \
          const float w = GA[2 * kk];                                         \
          h0a = fmaf(w, v.z, h0a); h0b = fmaf(w, v.w, h0b);                   \
          h0q = fmaf(w, qv_, h0q); h0p = fmaf(w, pv_, h0p);                   \
        }                                                                     \
        if (kk >= 1) {                                                        \
          const float w = GA[2 * kk - 1];                                     \
          h1a = fmaf(w, v.z, h1a); h1b = fmaf(w, v.w, h1b);                   \
          h1q = fmaf(w, qv_, h1q); h1p = fmaf(w, pv_, h1p);                   \
        }                                                                     \
      }                                                                       \
    }                                                                         \
    xA##S = h0a; xB##S = h0b; xQ##S = h0q; xP##S = h0p;                       \
    yA##S = h1a; yB##S = h1b; yQ##S = h1q; yP##S = h1p;                       \
  }

  // Vertical conv: explicit rotation, slot names literal.
#define VC(P, s0,s1,s2v,s3,s4v,s5,s6v,s7,s8,s9,s10)                           \
  fmaf(GA[10], P##s10, fmaf(GA[9], P##s9, fmaf(GA[8], P##s8,                  \
  fmaf(GA[7], P##s7, fmaf(GA[6], P##s6v, fmaf(GA[5], P##s5,                   \
  fmaf(GA[4], P##s4v, fmaf(GA[3], P##s3, fmaf(GA[2], P##s2v,                  \
  fmaf(GA[1], P##s1, GA[0] * P##s0))))))))))

#define SSIMACC                                                               \
  {                                                                           \
    const float m1s = m1 * m1, m2s = m2 * m2, m12 = m1 * m2;                  \
    const float s12 = mp - m12;                                               \
    const float sqq = mq - m1s - m2s;                                         \
    const float num = fmaf(2.f, m12, C1v) * fmaf(2.f, s12, C2v);              \
    const float den = (m1s + m2s + C1v) * (sqq + C2v);                        \
    local = fmaf(num, __builtin_amdgcn_rcpf(den), local);                     \
  }

#define VOUTBODY(s0,s1,s2v,s3,s4v,s5,s6v,s7,s8,s9,s10)                        \
  {                                                                           \
    {                                                                         \
      const float m1 = VC(xA, s0,s1,s2v,s3,s4v,s5,s6v,s7,s8,s9,s10);          \
      const float m2 = VC(xB, s0,s1,s2v,s3,s4v,s5,s6v,s7,s8,s9,s10);          \
      const float mq = VC(xQ, s0,s1,s2v,s3,s4v,s5,s6v,s7,s8,s9,s10);          \
      const float mp = VC(xP, s0,s1,s2v,s3,s4v,s5,s6v,s7,s8,s9,s10);          \
      SSIMACC                                                                 \
    }                                                                         \
    {                                                                         \
      const float m1 = VC(yA, s0,s1,s2v,s3,s4v,s5,s6v,s7,s8,s9,s10);          \
      const float m2 = VC(yB, s0,s1,s2v,s3,s4v,s5,s6v,s7,s8,s9,s10);          \
      const float mq = VC(yQ, s0,s1,s2v,s3,s4v,s5,s6v,s7,s8,s9,s10);          \
      const float mp = VC(yP, s0,s1,s2v,s3,s4v,s5,s6v,s7,s8,s9,s10);          \
      SSIMACC                                                                 \
    }                                                                         \
  }

  // Rotations: output at input row rc taps ring slot (rc+1+i)%11 for tap i.
#define ROT0  0,1,2,3,4,5,6,7,8,9,10
#define ROT1  1,2,3,4,5,6,7,8,9,10,0
#define ROT2  2,3,4,5,6,7,8,9,10,0,1
#define ROT3  3,4,5,6,7,8,9,10,0,1,2
#define ROT4  4,5,6,7,8,9,10,0,1,2,3
#define ROT5  5,6,7,8,9,10,0,1,2,3,4
#define ROT6  6,7,8,9,10,0,1,2,3,4,5
#define ROT7  7,8,9,10,0,1,2,3,4,5,6
#define ROT8  8,9,10,0,1,2,3,4,5,6,7
#define ROT9  9,10,0,1,2,3,4,5,6,7,8
#define ROT10 10,0,1,2,3,4,5,6,7,8,9
#define VOUTE(...) VOUTBODY(__VA_ARGS__)

#define ROWH(B_, j_, S)        { HBODY(B_, j_, S) }
#define ROWO(B_, j_, S, R_)    { HBODY(B_, j_, S) VOUTE(R_) }

  // Prologue: stage chunk 0 (buf0), prefetch chunk 1 regs.
  LOADC(0) WRITEC(0) LOADC(1)
  __syncthreads();

  // Steady state: per chunk k — write prefetched chunk k+1 (opposite
  // buffer; its readers retired at the previous barrier), issue loads for
  // k+2 (latency hides under this chunk's compute), compute chunk k,
  // barrier. rc = 4k+j, ring slot S = rc%11, output when rc >= 10.
  // k=0: rc 0-3
  WRITEC(1) LOADC(2)
  ROWH(0,0,0) ROWH(0,1,1) ROWH(0,2,2) ROWH(0,3,3)
  __syncthreads();
  // k=1: rc 4-7
  WRITEC(2) LOADC(3)
  ROWH(1,0,4) ROWH(1,1,5) ROWH(1,2,6) ROWH(1,3,7)
  __syncthreads();
  // k=2: rc 8-11 (rc10,11 emit output rows 0,1)
  WRITEC(3) LOADC(4)
  ROWH(0,0,8) ROWH(0,1,9)
  ROWO(0,2,10, ROT0) ROWO(0,3,0, ROT1)
  __syncthreads();
  // k=3: rc 12-15
  WRITEC(4) LOADC(5)
  ROWO(1,0,1, ROT2) ROWO(1,1,2, ROT3) ROWO(1,2,3, ROT4) ROWO(1,3,4, ROT5)
  __syncthreads();
  // k=4: rc 16-19
  WRITEC(5) LOADC(6)
  ROWO(0,0,5, ROT6) ROWO(0,1,6, ROT7) ROWO(0,2,7, ROT8) ROWO(0,3,8, ROT9)
  __syncthreads();
  // k=5: rc 20-23
  WRITEC(6) LOADC(7)
  ROWO(1,0,9, ROT10) ROWO(1,1,10, ROT0) ROWO(1,2,0, ROT1) ROWO(1,3,1, ROT2)
  __syncthreads();
  // k=6: rc 24-27
  WRITEC(7) LOADC(8)
  ROWO(0,0,2, ROT3) ROWO(0,1,3, ROT4) ROWO(0,2,4, ROT5) ROWO(0,3,5, ROT6)
  __syncthreads();
  // k=7: rc 28-31
  WRITEC(8) LOADC(9)
  ROWO(1,0,6, ROT7) ROWO(1,1,7, ROT8) ROWO(1,2,8, ROT9) ROWO(1,3,9, ROT10)
  __syncthreads();
  // k=8: rc 32-35
  WRITEC(9) LOADC(10)
  ROWO(0,0,10, ROT0) ROWO(0,1,0, ROT1) ROWO(0,2,1, ROT2) ROWO(0,3,2, ROT3)
  __syncthreads();
  // k=9: rc 36-39 (chunk 10 has only rows rc 40,41; rc 42,43 constexpr-cut)
  WRITEC(10)
  ROWO(1,0,3, ROT4) ROWO(1,1,4, ROT5) ROWO(1,2,5, ROT6) ROWO(1,3,6, ROT7)
  __syncthreads();
  // k=10: rc 40,41 (output rows 30,31)
  ROWO(0,0,7, ROT8) ROWO(0,1,8, ROT9)

  // Block reduction: wave64 shuffle -> LDS -> one double atomic per block.
#pragma unroll
  for (int off = 32; off > 0; off >>= 1) local += __shfl_down(local, off, 64);
  const int wave = t >> 6;
  const int lane = t & 63;
  if (lane == 0) wsum[wave] = local;
  __syncthreads();
  if (t == 0) {
    float s = wsum[0] + wsum[1] + wsum[2] + wsum[3];
    atomicAdd(accum, (double)s);
  }
}

__global__ void ssim_final_kernel(const double* __restrict__ accum,
                                  float* __restrict__ out) {
  out[0] = 1.0f - (float)(accum[0] / NPIX);
}

extern "C" void kernel_launch(void* const* d_in, const int* in_sizes, int n_in,
                              void* d_out, int out_size, void* d_ws, size_t ws_size,
                              hipStream_t stream) {
  const float* img1 = (const float*)d_in[0];
  const float* img2 = (const float*)d_in[1];
  double* accum = (double*)d_ws;
  hipMemsetAsync(accum, 0, sizeof(double), stream);

  dim3 grid(HH / TH, BATCH);
  ssim_main_kernel<<<grid, 256, 0, stream>>>(img1, img2, accum);
  ssim_final_kernel<<<1, 1, 0, stream>>>(accum, (float*)d_out);
}